// Round 1
// baseline (188.735 us; speedup 1.0000x reference)
//
#include <hip/hip_runtime.h>
#include <hip/hip_bf16.h>

// AFT-Full: out = (exp(w) @ (exp(K)*V)) / (exp(w) @ exp(K)),  K,V = x@W+b
// B=8, T=2048, DIM=1024, HID=128. All inputs fp32; compute in bf16 MFMA.

#define T_     2048
#define DIM_   1024
#define HID_   128
#define BATCH_ 8
#define M1_    (BATCH_ * T_)   // 16384

typedef __attribute__((ext_vector_type(8))) __bf16 bf16x8;
typedef __attribute__((ext_vector_type(4))) float f32x4;
typedef __attribute__((ext_vector_type(4))) unsigned short us4;
typedef __attribute__((ext_vector_type(8))) unsigned short us8;

__device__ __forceinline__ unsigned short f2bf(float f) {
    unsigned int u = __builtin_bit_cast(unsigned int, f);
    u += 0x7fffu + ((u >> 16) & 1u);   // RNE
    return (unsigned short)(u >> 16);
}

// ---------------------------------------------------------------- prep_ew
// ew_bf16[t][s] = bf16(exp(w[t][s]))     (2048x2048)
__global__ __launch_bounds__(256) void prep_ew(const float* __restrict__ w,
                                               unsigned short* __restrict__ ew) {
    int idx = blockIdx.x * 256 + threadIdx.x;   // float4 index, 1M total
    f32x4 v = ((const f32x4*)w)[idx];
    us4 o;
    o[0] = f2bf(__expf(v[0]));
    o[1] = f2bf(__expf(v[1]));
    o[2] = f2bf(__expf(v[2]));
    o[3] = f2bf(__expf(v[3]));
    ((us4*)ew)[idx] = o;
}

// ---------------------------------------------------------------- prep_wkv
// wkvT[n][k]: n<128 -> wk_w[k][n], else wv_w[k][n-128]   (256 x 1024 bf16)
__global__ __launch_bounds__(256) void prep_wkv(const float* __restrict__ wk,
                                                const float* __restrict__ wv,
                                                unsigned short* __restrict__ wkvT) {
    int t = blockIdx.x * 256 + threadIdx.x;   // 262144 total
    int n = t & 255, k = t >> 8;
    float v = (n < 128) ? wk[k * 128 + n] : wv[k * 128 + (n - 128)];
    wkvT[n * 1024 + k] = f2bf(v);
}

// ---------------------------------------------------------------- gemm1
// KVraw[s][n] = x[s][:] @ wkvT[n][:] + bias[n]   (fp32, 16384 x 256)
// BM=128 BN=128 BK=64, 4 waves, wave tile 64x64 (4x4 frags of 16x16x32)
__global__ __launch_bounds__(256) void gemm1(const float* __restrict__ x,
                                             const unsigned short* __restrict__ wkvT,
                                             const float* __restrict__ wk_b,
                                             const float* __restrict__ wv_b,
                                             float* __restrict__ KVraw) {
    __shared__ __align__(16) unsigned short As[128 * 72];
    __shared__ __align__(16) unsigned short Bs[128 * 72];
    const int tid = threadIdx.x;
    const int m0 = blockIdx.x * 128;
    const int n0 = blockIdx.y * 128;
    const int wave = tid >> 6, lane = tid & 63;
    const int wr = wave >> 1, wc = wave & 1;
    const int lr = lane & 15, lq = lane >> 4;

    f32x4 acc[4][4];
#pragma unroll
    for (int i = 0; i < 4; i++)
#pragma unroll
        for (int j = 0; j < 4; j++) acc[i][j] = {0.f, 0.f, 0.f, 0.f};

    for (int k0 = 0; k0 < DIM_; k0 += 64) {
        // stage A: 128x64 fp32 -> bf16 into LDS (padded stride 72)
#pragma unroll
        for (int i = 0; i < 8; i++) {
            int chunk = tid + i * 256;            // [0,2048) float4 chunks
            int r = chunk >> 4, c4 = (chunk & 15) * 4;
            f32x4 v = *(const f32x4*)(x + (size_t)(m0 + r) * DIM_ + k0 + c4);
            us4 o;
            o[0] = f2bf(v[0]); o[1] = f2bf(v[1]);
            o[2] = f2bf(v[2]); o[3] = f2bf(v[3]);
            *(us4*)(&As[r * 72 + c4]) = o;
        }
        // stage B: 128x64 bf16
#pragma unroll
        for (int i = 0; i < 4; i++) {
            int chunk = tid + i * 256;            // [0,1024) 8-elem chunks
            int r = chunk >> 3, c8 = (chunk & 7) * 8;
            us8 v = *(const us8*)(wkvT + (size_t)(n0 + r) * DIM_ + k0 + c8);
            *(us8*)(&Bs[r * 72 + c8]) = v;
        }
        __syncthreads();
#pragma unroll
        for (int ks = 0; ks < 64; ks += 32) {
            bf16x8 af[4], bfr[4];
#pragma unroll
            for (int mf = 0; mf < 4; mf++)
                af[mf] = *(const bf16x8*)(&As[(wr * 64 + mf * 16 + lr) * 72 + ks + lq * 8]);
#pragma unroll
            for (int nf = 0; nf < 4; nf++)
                bfr[nf] = *(const bf16x8*)(&Bs[(wc * 64 + nf * 16 + lr) * 72 + ks + lq * 8]);
#pragma unroll
            for (int mf = 0; mf < 4; mf++)
#pragma unroll
                for (int nf = 0; nf < 4; nf++)
                    acc[mf][nf] = __builtin_amdgcn_mfma_f32_16x16x32_bf16(
                        af[mf], bfr[nf], acc[mf][nf], 0, 0, 0);
        }
        __syncthreads();
    }
    // epilogue: + bias, write raw fp32
#pragma unroll
    for (int nf = 0; nf < 4; nf++) {
        int ng = n0 + wc * 64 + nf * 16 + lr;       // [0,256)
        float bias = (ng < 128) ? wk_b[ng] : wv_b[ng - 128];
#pragma unroll
        for (int mf = 0; mf < 4; mf++) {
            int mb = m0 + wr * 64 + mf * 16 + lq * 4;
#pragma unroll
            for (int j = 0; j < 4; j++)
                KVraw[(size_t)(mb + j) * 256 + ng] = acc[mf][nf][j] + bias;
        }
    }
}

// ---------------------------------------------------------------- trans_ek
// eKT[b][h][t] = bf16(exp(K)), eKVT[b][h][t] = bf16(exp(K)*V)
__global__ __launch_bounds__(256) void trans_ek(const float* __restrict__ KVraw,
                                                unsigned short* __restrict__ eKT,
                                                unsigned short* __restrict__ eKVT) {
    __shared__ __align__(16) unsigned short ekS[64 * 68];
    __shared__ __align__(16) unsigned short ekvS[64 * 68];
    const int tid = threadIdx.x;
    const int t0 = blockIdx.x * 64, h0 = blockIdx.y * 64, b = blockIdx.z;
#pragma unroll
    for (int i = 0; i < 4; i++) {
        int chunk = tid + i * 256;                // [0,1024)
        int r = chunk >> 4, c4 = (chunk & 15) * 4;
        const float* base = KVraw + (size_t)(b * T_ + t0 + r) * 256 + h0 + c4;
        f32x4 kv = *(const f32x4*)(base);
        f32x4 vv = *(const f32x4*)(base + 128);
        us4 ok, okv;
#pragma unroll
        for (int j = 0; j < 4; j++) {
            float ek = __expf(kv[j]);
            ok[j]  = f2bf(ek);
            okv[j] = f2bf(ek * vv[j]);
        }
        *(us4*)(&ekS[r * 68 + c4])  = ok;
        *(us4*)(&ekvS[r * 68 + c4]) = okv;
    }
    __syncthreads();
#pragma unroll
    for (int i = 0; i < 2; i++) {
        int chunk = tid + i * 256;                // [0,512)
        int h = chunk >> 3, tt0 = (chunk & 7) * 8;
        us8 vk, vkv;
#pragma unroll
        for (int j = 0; j < 8; j++) {
            vk[j]  = ekS[(tt0 + j) * 68 + h];
            vkv[j] = ekvS[(tt0 + j) * 68 + h];
        }
        size_t o = (size_t)b * (HID_ * T_) + (size_t)(h0 + h) * T_ + t0 + tt0;
        *(us8*)(&eKT[o])  = vk;
        *(us8*)(&eKVT[o]) = vkv;
    }
}

// ---------------------------------------------------------------- gemm2
// half==0: num[b][t][h] = ew[t][:] @ eKVT[b][h][:]
// half==1: den[b][t][h] = ew[t][:] @ eKT[b][h][:]
__global__ __launch_bounds__(256) void gemm2(const unsigned short* __restrict__ ew,
                                             const unsigned short* __restrict__ eKVT,
                                             const unsigned short* __restrict__ eKT,
                                             float* __restrict__ num,
                                             float* __restrict__ den) {
    __shared__ __align__(16) unsigned short As[128 * 72];
    __shared__ __align__(16) unsigned short Bs[128 * 72];
    const int tid = threadIdx.x;
    const int t0 = blockIdx.x * 128;
    const int b = blockIdx.y >> 1, half = blockIdx.y & 1;
    const unsigned short* Bsrc = (half ? eKT : eKVT) + (size_t)b * HID_ * T_;
    float* outw = (half ? den : num) + (size_t)b * T_ * HID_;
    const int wave = tid >> 6, lane = tid & 63;
    const int wr = wave >> 1, wc = wave & 1;
    const int lr = lane & 15, lq = lane >> 4;

    f32x4 acc[4][4];
#pragma unroll
    for (int i = 0; i < 4; i++)
#pragma unroll
        for (int j = 0; j < 4; j++) acc[i][j] = {0.f, 0.f, 0.f, 0.f};

    for (int k0 = 0; k0 < T_; k0 += 64) {
#pragma unroll
        for (int i = 0; i < 4; i++) {
            int chunk = tid + i * 256;
            int r = chunk >> 3, c8 = (chunk & 7) * 8;
            us8 v = *(const us8*)(ew + (size_t)(t0 + r) * T_ + k0 + c8);
            *(us8*)(&As[r * 72 + c8]) = v;
        }
#pragma unroll
        for (int i = 0; i < 4; i++) {
            int chunk = tid + i * 256;
            int r = chunk >> 3, c8 = (chunk & 7) * 8;
            us8 v = *(const us8*)(Bsrc + (size_t)r * T_ + k0 + c8);
            *(us8*)(&Bs[r * 72 + c8]) = v;
        }
        __syncthreads();
#pragma unroll
        for (int ks = 0; ks < 64; ks += 32) {
            bf16x8 af[4], bfr[4];
#pragma unroll
            for (int mf = 0; mf < 4; mf++)
                af[mf] = *(const bf16x8*)(&As[(wr * 64 + mf * 16 + lr) * 72 + ks + lq * 8]);
#pragma unroll
            for (int nf = 0; nf < 4; nf++)
                bfr[nf] = *(const bf16x8*)(&Bs[(wc * 64 + nf * 16 + lr) * 72 + ks + lq * 8]);
#pragma unroll
            for (int mf = 0; mf < 4; mf++)
#pragma unroll
                for (int nf = 0; nf < 4; nf++)
                    acc[mf][nf] = __builtin_amdgcn_mfma_f32_16x16x32_bf16(
                        af[mf], bfr[nf], acc[mf][nf], 0, 0, 0);
        }
        __syncthreads();
    }
#pragma unroll
    for (int nf = 0; nf < 4; nf++) {
        int h = wc * 64 + nf * 16 + lr;            // [0,128)
#pragma unroll
        for (int mf = 0; mf < 4; mf++) {
            int t = t0 + wr * 64 + mf * 16 + lq * 4;
#pragma unroll
            for (int j = 0; j < 4; j++)
                outw[(size_t)(t + j) * HID_ + h] = acc[mf][nf][j];
        }
    }
}

// ---------------------------------------------------------------- divide
__global__ __launch_bounds__(256) void divide_k(const float* __restrict__ num,
                                                const float* __restrict__ den,
                                                float* __restrict__ out) {
    int i = blockIdx.x * 256 + threadIdx.x;       // float4 index, 512K total
    f32x4 n = ((const f32x4*)num)[i];
    f32x4 d = ((const f32x4*)den)[i];
    f32x4 o = {n[0] / d[0], n[1] / d[1], n[2] / d[2], n[3] / d[3]};
    ((f32x4*)out)[i] = o;
}

// ---------------------------------------------------------------- launch
extern "C" void kernel_launch(void* const* d_in, const int* in_sizes, int n_in,
                              void* d_out, int out_size, void* d_ws, size_t ws_size,
                              hipStream_t stream) {
    const float* x    = (const float*)d_in[0];
    const float* wk_w = (const float*)d_in[1];
    const float* wk_b = (const float*)d_in[2];
    const float* wv_w = (const float*)d_in[3];
    const float* wv_b = (const float*)d_in[4];
    const float* w    = (const float*)d_in[5];

    char* ws = (char*)d_ws;
    unsigned short* ws_ew   = (unsigned short*)(ws);                    // 8 MiB  [2048][2048] bf16
    unsigned short* ws_wkvT = (unsigned short*)(ws + (8u  << 20));      // 0.5MiB [256][1024]  bf16
    float*          ws_KV   = (float*)         (ws + (9u  << 20));      // 16 MiB [16384][256] f32
    unsigned short* ws_eKT  = (unsigned short*)(ws + (25u << 20));      // 4 MiB  [8][128][2048]
    unsigned short* ws_eKVT = (unsigned short*)(ws + (29u << 20));      // 4 MiB
    float*          ws_num  = (float*)         (ws + (33u << 20));      // 8 MiB  [8][2048][128]
    float*          ws_den  = (float*)         (ws + (41u << 20));      // 8 MiB  (total 49 MiB)

    prep_ew  <<<4096, 256, 0, stream>>>(w, ws_ew);
    prep_wkv <<<1024, 256, 0, stream>>>(wk_w, wv_w, ws_wkvT);
    gemm1    <<<dim3(128, 2), 256, 0, stream>>>(x, ws_wkvT, wk_b, wv_b, ws_KV);
    trans_ek <<<dim3(32, 2, 8), 256, 0, stream>>>(ws_KV, ws_eKT, ws_eKVT);
    gemm2    <<<dim3(16, 16), 256, 0, stream>>>(ws_ew, ws_eKVT, ws_eKT, ws_num, ws_den);
    divide_k <<<2048, 256, 0, stream>>>(ws_num, ws_den, (float*)d_out);
}

// Round 3
// 183.681 us; speedup vs baseline: 1.0275x; 1.0275x over previous
//
#include <hip/hip_runtime.h>
#include <hip/hip_bf16.h>

// AFT-Full: out = (exp(w) @ (exp(K)*V)) / (exp(w) @ exp(K)),  K,V = x@W+b
// B=8, T=2048, DIM=1024, HID=128. fp32 in/out; bf16 MFMA internally.
// Pipeline: prep_ew, prep_wkv, gemm1(+exp/pair/transpose epilogue),
//           gemm2(num+den fused, divide in epilogue).

#define T_    2048
#define DIM_  1024
#define HID_  128

typedef __attribute__((ext_vector_type(8))) __bf16 bf16x8;
typedef __attribute__((ext_vector_type(4))) float f32x4;
typedef __attribute__((ext_vector_type(4))) unsigned short us4;
typedef __attribute__((ext_vector_type(8))) unsigned short us8;

typedef const unsigned int __attribute__((address_space(1)))* gas_t;
typedef unsigned int __attribute__((address_space(3)))* las_t;

__device__ __forceinline__ unsigned short f2bf(float f) {
    unsigned int u = __builtin_bit_cast(unsigned int, f);
    u += 0x7fffu + ((u >> 16) & 1u);   // RNE
    return (unsigned short)(u >> 16);
}

__device__ __forceinline__ void gload16(const void* g, void* l) {
    __builtin_amdgcn_global_load_lds((gas_t)g, (las_t)l, 16, 0, 0);
}

// ---------------------------------------------------------------- prep_ew
__global__ __launch_bounds__(256) void prep_ew(const float* __restrict__ w,
                                               unsigned short* __restrict__ ew) {
    int idx = blockIdx.x * 256 + threadIdx.x;   // float4 index, 1M total
    f32x4 v = ((const f32x4*)w)[idx];
    us4 o;
    o[0] = f2bf(__expf(v[0]));
    o[1] = f2bf(__expf(v[1]));
    o[2] = f2bf(__expf(v[2]));
    o[3] = f2bf(__expf(v[3]));
    ((us4*)ew)[idx] = o;
}

// ---------------------------------------------------------------- prep_wkv
// wkvT[n][k]: n<128 -> wk_w[k][n], else wv_w[k][n-128]   (256 x 1024 bf16)
__global__ __launch_bounds__(256) void prep_wkv(const float* __restrict__ wk,
                                                const float* __restrict__ wv,
                                                unsigned short* __restrict__ wkvT) {
    int t = blockIdx.x * 256 + threadIdx.x;
    int n = t & 255, k = t >> 8;
    float v = (n < 128) ? wk[k * 128 + n] : wv[k * 128 + (n - 128)];
    wkvT[n * 1024 + k] = f2bf(v);
}

// ---------------------------------------------------------------- gemm1
// Computes K|V = x @ wkvT^T (+bias) for a 64-row tile, then in-epilogue:
// eK=exp(K), eKV=eK*V, transposed bf16 write into KVc[b]:
//   rows 0..127  = (eK*V)^T   (num operand)
//   rows 128..255 = (eK)^T    (den operand)
// BM=64, BN=256(full), BK=64, 4 waves; wave n-slice = 32 K-cols + 32 V-cols.
__global__ __launch_bounds__(256) void gemm1(const float* __restrict__ x,
                                             const unsigned short* __restrict__ wkvT,
                                             const float* __restrict__ wk_b,
                                             const float* __restrict__ wv_b,
                                             unsigned short* __restrict__ KVc) {
    __shared__ __align__(16) unsigned short As[2][64 * 72];    // padded (reg-staged)
    __shared__ __align__(16) unsigned short Bs[2][256 * 64];   // linear (gload_lds, swz)
    const int tid  = threadIdx.x;
    const int m0   = blockIdx.x * 64;          // [0,16384)
    const int bb   = m0 >> 11;
    const int t0   = m0 & (T_ - 1);
    const int wave = tid >> 6, lane = tid & 63;
    const int lr = lane & 15, lq = lane >> 4;

    f32x4 acc[4][4];
#pragma unroll
    for (int i = 0; i < 4; i++)
#pragma unroll
        for (int j = 0; j < 4; j++) acc[i][j] = {0.f, 0.f, 0.f, 0.f};

    f32x4 areg[4];
    // ---- prologue: stage k0=0 into buf 0
#pragma unroll
    for (int i = 0; i < 4; i++) {
        int c = i * 256 + tid, r = c >> 4, c4 = (c & 15) * 4;
        areg[i] = *(const f32x4*)(x + (size_t)(m0 + r) * DIM_ + c4);
    }
#pragma unroll
    for (int i = 0; i < 8; i++) {
        int c = i * 256 + tid, r = c >> 3, kc = ((c & 7) ^ (r & 7)) * 8;
        gload16(wkvT + (size_t)r * DIM_ + kc, &Bs[0][(i * 256 + wave * 64) * 8]);
    }
#pragma unroll
    for (int i = 0; i < 4; i++) {
        int c = i * 256 + tid, r = c >> 4, c4 = (c & 15) * 4;
        us4 o;
        o[0] = f2bf(areg[i][0]); o[1] = f2bf(areg[i][1]);
        o[2] = f2bf(areg[i][2]); o[3] = f2bf(areg[i][3]);
        *(us4*)(&As[0][r * 72 + c4]) = o;
    }
    __syncthreads();

    int buf = 0;
    for (int t = 0; t < 16; t++) {
        if (t < 15) {                         // issue next-tile loads first
            int k0 = (t + 1) * 64;
#pragma unroll
            for (int i = 0; i < 4; i++) {
                int c = i * 256 + tid, r = c >> 4, c4 = (c & 15) * 4;
                areg[i] = *(const f32x4*)(x + (size_t)(m0 + r) * DIM_ + k0 + c4);
            }
#pragma unroll
            for (int i = 0; i < 8; i++) {
                int c = i * 256 + tid, r = c >> 3, kc = ((c & 7) ^ (r & 7)) * 8;
                gload16(wkvT + (size_t)r * DIM_ + k0 + kc,
                        &Bs[buf ^ 1][(i * 256 + wave * 64) * 8]);
            }
        }
#pragma unroll
        for (int ks = 0; ks < 64; ks += 32) {
            bf16x8 af[4], bfr[4];
#pragma unroll
            for (int mf = 0; mf < 4; mf++)
                af[mf] = *(const bf16x8*)(&As[buf][(mf * 16 + lr) * 72 + ks + lq * 8]);
#pragma unroll
            for (int nf = 0; nf < 4; nf++) {
                int rb = (nf < 2) ? (wave * 32 + nf * 16 + lr)
                                  : (128 + wave * 32 + (nf - 2) * 16 + lr);
                bfr[nf] = *(const bf16x8*)(&Bs[buf][rb * 64 + ((ks + lq * 8) ^ ((rb & 7) << 3))]);
            }
#pragma unroll
            for (int mf = 0; mf < 4; mf++)
#pragma unroll
                for (int nf = 0; nf < 4; nf++)
                    acc[mf][nf] = __builtin_amdgcn_mfma_f32_16x16x32_bf16(
                        af[mf], bfr[nf], acc[mf][nf], 0, 0, 0);
        }
        if (t < 15) {                         // convert arrived A into other buf
#pragma unroll
            for (int i = 0; i < 4; i++) {
                int c = i * 256 + tid, r = c >> 4, c4 = (c & 15) * 4;
                us4 o;
                o[0] = f2bf(areg[i][0]); o[1] = f2bf(areg[i][1]);
                o[2] = f2bf(areg[i][2]); o[3] = f2bf(areg[i][3]);
                *(us4*)(&As[buf ^ 1][r * 72 + c4]) = o;
            }
        }
        __syncthreads();
        buf ^= 1;
    }

    // ---- epilogue: eK/eKV + transpose via LDS (overlay on Bs), bf16 write
    unsigned short* ekvS = &Bs[0][0];           // [128][72]
    unsigned short* ekS  = ekvS + 128 * 72;     // [128][72]
#pragma unroll
    for (int nf = 0; nf < 2; nf++) {
        int h = wave * 32 + nf * 16 + lr;       // [0,128)
        float bk = wk_b[h], bv = wv_b[h];
#pragma unroll
        for (int mf = 0; mf < 4; mf++) {
            int m = mf * 16 + lq * 4;
            us4 ok, okv;
#pragma unroll
            for (int j = 0; j < 4; j++) {
                float ek = __expf(acc[mf][nf][j] + bk);
                float vv = acc[mf][nf + 2][j] + bv;
                ok[j]  = f2bf(ek);
                okv[j] = f2bf(ek * vv);
            }
            *(us4*)(ekS  + h * 72 + m) = ok;
            *(us4*)(ekvS + h * 72 + m) = okv;
        }
    }
    __syncthreads();
    unsigned short* dst = KVc + (size_t)bb * 256 * T_;
#pragma unroll
    for (int i = 0; i < 4; i++) {
        int c = i * 256 + tid;                  // 1024 chunks of us8
        int h = c >> 3, mc = (c & 7) * 8;
        us8 vkv = *(const us8*)(ekvS + h * 72 + mc);
        us8 vk  = *(const us8*)(ekS  + h * 72 + mc);
        *(us8*)(dst + (size_t)h * T_ + t0 + mc)         = vkv;   // num rows
        *(us8*)(dst + (size_t)(128 + h) * T_ + t0 + mc) = vk;    // den rows
    }
}

// ---------------------------------------------------------------- gemm2
// out[b][t][h] = (ew[t,:] @ eKV^T[h,:]) / (ew[t,:] @ eK^T[h,:])
// BM=64 (t), BN=256 (128 num + 128 den), BK=64, K=2048, 4 waves.
// Wave wc covers num cols [wc*32, wc*32+32) and den cols [128+wc*32, ...):
// divide is register-local (acc[:,nf] / acc[:,nf+2]).
__global__ __launch_bounds__(256) void gemm2(const unsigned short* __restrict__ ew,
                                             const unsigned short* __restrict__ KVc,
                                             float* __restrict__ out) {
    __shared__ __align__(16) unsigned short As[2][64 * 64];
    __shared__ __align__(16) unsigned short Bs[2][256 * 64];
    const int tid  = threadIdx.x;
    const int t0   = blockIdx.x * 64;
    const int b    = blockIdx.y;
    const unsigned short* Bsrc = KVc + (size_t)b * 256 * T_;
    const int wave = tid >> 6, lane = tid & 63;
    const int lr = lane & 15, lq = lane >> 4;

    f32x4 acc[4][4];
#pragma unroll
    for (int i = 0; i < 4; i++)
#pragma unroll
        for (int j = 0; j < 4; j++) acc[i][j] = {0.f, 0.f, 0.f, 0.f};

    // ---- prologue: stage k0=0 into buf 0 (swizzled source, linear LDS)
#pragma unroll
    for (int i = 0; i < 2; i++) {
        int c = i * 256 + tid, r = c >> 3, kc = ((c & 7) ^ (r & 7)) * 8;
        gload16(ew + (size_t)(t0 + r) * T_ + kc, &As[0][(i * 256 + wave * 64) * 8]);
    }
#pragma unroll
    for (int i = 0; i < 8; i++) {
        int c = i * 256 + tid, r = c >> 3, kc = ((c & 7) ^ (r & 7)) * 8;
        gload16(Bsrc + (size_t)r * T_ + kc, &Bs[0][(i * 256 + wave * 64) * 8]);
    }
    __syncthreads();

    int buf = 0;
    for (int t = 0; t < 32; t++) {
        if (t < 31) {
            int k0 = (t + 1) * 64;
#pragma unroll
            for (int i = 0; i < 2; i++) {
                int c = i * 256 + tid, r = c >> 3, kc = ((c & 7) ^ (r & 7)) * 8;
                gload16(ew + (size_t)(t0 + r) * T_ + k0 + kc,
                        &As[buf ^ 1][(i * 256 + wave * 64) * 8]);
            }
#pragma unroll
            for (int i = 0; i < 8; i++) {
                int c = i * 256 + tid, r = c >> 3, kc = ((c & 7) ^ (r & 7)) * 8;
                gload16(Bsrc + (size_t)r * T_ + k0 + kc,
                        &Bs[buf ^ 1][(i * 256 + wave * 64) * 8]);
            }
        }
#pragma unroll
        for (int ks = 0; ks < 64; ks += 32) {
            bf16x8 af[4], bfr[4];
#pragma unroll
            for (int mf = 0; mf < 4; mf++) {
                int ra = mf * 16 + lr;
                af[mf] = *(const bf16x8*)(&As[buf][ra * 64 + ((ks + lq * 8) ^ ((ra & 7) << 3))]);
            }
#pragma unroll
            for (int nf = 0; nf < 4; nf++) {
                int rb = (nf < 2) ? (wave * 32 + nf * 16 + lr)
                                  : (128 + wave * 32 + (nf - 2) * 16 + lr);
                bfr[nf] = *(const bf16x8*)(&Bs[buf][rb * 64 + ((ks + lq * 8) ^ ((rb & 7) << 3))]);
            }
#pragma unroll
            for (int mf = 0; mf < 4; mf++)
#pragma unroll
                for (int nf = 0; nf < 4; nf++)
                    acc[mf][nf] = __builtin_amdgcn_mfma_f32_16x16x32_bf16(
                        af[mf], bfr[nf], acc[mf][nf], 0, 0, 0);
        }
        __syncthreads();
        buf ^= 1;
    }

    // ---- epilogue: register-local divide, fp32 store
    float* ob = out + ((size_t)b * T_ + t0) * HID_;
#pragma unroll
    for (int nf = 0; nf < 2; nf++) {
        int h = wave * 32 + nf * 16 + lr;
#pragma unroll
        for (int mf = 0; mf < 4; mf++) {
            int m = mf * 16 + lq * 4;
#pragma unroll
            for (int j = 0; j < 4; j++)
                ob[(size_t)(m + j) * HID_ + h] = acc[mf][nf][j] / acc[mf][nf + 2][j];
        }
    }
}

// ---------------------------------------------------------------- launch
extern "C" void kernel_launch(void* const* d_in, const int* in_sizes, int n_in,
                              void* d_out, int out_size, void* d_ws, size_t ws_size,
                              hipStream_t stream) {
    const float* x    = (const float*)d_in[0];
    const float* wk_w = (const float*)d_in[1];
    const float* wk_b = (const float*)d_in[2];
    const float* wv_w = (const float*)d_in[3];
    const float* wv_b = (const float*)d_in[4];
    const float* w    = (const float*)d_in[5];

    char* ws = (char*)d_ws;
    unsigned short* ws_ew   = (unsigned short*)(ws);                 // 8 MiB [2048][2048]
    unsigned short* ws_wkvT = (unsigned short*)(ws + (8u << 20));    // 0.5 MiB [256][1024]
    unsigned short* ws_KVc  = (unsigned short*)(ws + (9u << 20));    // 8 MiB [8][256][2048]

    prep_ew  <<<4096, 256, 0, stream>>>(w, ws_ew);
    prep_wkv <<<1024, 256, 0, stream>>>(wk_w, wv_w, ws_wkvT);
    gemm1    <<<256, 256, 0, stream>>>(x, ws_wkvT, wk_b, wv_b, ws_KVc);
    gemm2    <<<dim3(32, 8), 256, 0, stream>>>(ws_ew, ws_KVc, (float*)d_out);
}

// Round 5
// 168.001 us; speedup vs baseline: 1.1234x; 1.0933x over previous
//
#include <hip/hip_runtime.h>
#include <hip/hip_bf16.h>

// AFT-Full: out = (exp(w) @ (exp(K)*V)) / (exp(w) @ exp(K)),  K,V = x@W+b
// B=8, T=2048, DIM=1024, HID=128. fp32 in/out; bf16 MFMA internally.
// R4: single-buffer m97 2-barrier structure, small LDS, 512-block grids
//     (fixes R3's 1-block/CU latency wall).

#define T_    2048
#define DIM_  1024
#define HID_  128

typedef __attribute__((ext_vector_type(8))) __bf16 bf16x8;
typedef __attribute__((ext_vector_type(4))) float f32x4;
typedef __attribute__((ext_vector_type(4))) unsigned short us4;
typedef __attribute__((ext_vector_type(8))) unsigned short us8;

typedef const unsigned int __attribute__((address_space(1)))* gas_t;
typedef unsigned int __attribute__((address_space(3)))* las_t;

__device__ __forceinline__ unsigned short f2bf(float f) {
    unsigned int u = __builtin_bit_cast(unsigned int, f);
    u += 0x7fffu + ((u >> 16) & 1u);   // RNE
    return (unsigned short)(u >> 16);
}

__device__ __forceinline__ void gload16(const void* g, void* l) {
    __builtin_amdgcn_global_load_lds((gas_t)g, (las_t)l, 16, 0, 0);
}

// ---------------------------------------------------------------- prep_ew
__global__ __launch_bounds__(256) void prep_ew(const float* __restrict__ w,
                                               unsigned short* __restrict__ ew) {
    int idx = blockIdx.x * 256 + threadIdx.x;   // float4 index, 1M total
    f32x4 v = ((const f32x4*)w)[idx];
    us4 o;
    o[0] = f2bf(__expf(v[0]));
    o[1] = f2bf(__expf(v[1]));
    o[2] = f2bf(__expf(v[2]));
    o[3] = f2bf(__expf(v[3]));
    ((us4*)ew)[idx] = o;
}

// ---------------------------------------------------------------- prep_wkv
// wkvT[n][k]: n<128 -> wk_w[k][n], else wv_w[k][n-128]   (256 x 1024 bf16)
__global__ __launch_bounds__(256) void prep_wkv(const float* __restrict__ wk,
                                                const float* __restrict__ wv,
                                                unsigned short* __restrict__ wkvT) {
    int t = blockIdx.x * 256 + threadIdx.x;
    int n = t & 255, k = t >> 8;
    float v = (n < 128) ? wk[k * 128 + n] : wv[k * 128 + (n - 128)];
    wkvT[n * 1024 + k] = f2bf(v);
}

// ---------------------------------------------------------------- gemm1
// K|V = x @ wkvT^T (+bias) for a 32-row tile; epilogue: eK=exp(K),
// eKV=eK*V, transposed bf16 write into KVc[b]:
//   rows 0..127   = (eK*V)^T  (num operand)
//   rows 128..255 = (eK)^T    (den operand)
// BM=32, BN=256(full), BK=64, 4 waves. Wave n-slice: K cols [w*32,w*32+32)
// paired with V cols [128+w*32, ...). acc[2][4]. Grid 512, LDS ~37KB.
__global__ __launch_bounds__(256) void gemm1(const float* __restrict__ x,
                                             const unsigned short* __restrict__ wkvT,
                                             const float* __restrict__ wk_b,
                                             const float* __restrict__ wv_b,
                                             unsigned short* __restrict__ KVc) {
    __shared__ __align__(16) unsigned short As[32 * 72];    // padded (reg-staged)
    __shared__ __align__(16) unsigned short Bs[256 * 64];   // linear (gload_lds, swz)
    const int tid  = threadIdx.x;
    const int m0   = blockIdx.x * 32;          // [0,16384)
    const int bb   = m0 >> 11;
    const int t0   = m0 & (T_ - 1);
    const int wave = tid >> 6, lane = tid & 63;
    const int lr = lane & 15, lq = lane >> 4;

    f32x4 acc[2][4];
#pragma unroll
    for (int i = 0; i < 2; i++)
#pragma unroll
        for (int j = 0; j < 4; j++) acc[i][j] = {0.f, 0.f, 0.f, 0.f};

    for (int t = 0; t < 16; t++) {
        int k0 = t * 64;
        __syncthreads();                       // LDS safe to overwrite
        // issue B staging (256x64 bf16, swizzled source, linear LDS dest)
#pragma unroll
        for (int i = 0; i < 8; i++) {
            int c = i * 256 + tid, r = c >> 3, kc = ((c & 7) ^ (r & 7)) * 8;
            gload16(wkvT + (size_t)r * DIM_ + k0 + kc, &Bs[(i * 256 + wave * 64) * 8]);
        }
        // A: 32x64 fp32 -> bf16, padded LDS
        f32x4 areg[2];
#pragma unroll
        for (int i = 0; i < 2; i++) {
            int c = i * 256 + tid, r = c >> 4, c4 = (c & 15) * 4;
            areg[i] = *(const f32x4*)(x + (size_t)(m0 + r) * DIM_ + k0 + c4);
        }
#pragma unroll
        for (int i = 0; i < 2; i++) {
            int c = i * 256 + tid, r = c >> 4, c4 = (c & 15) * 4;
            us4 o;
            o[0] = f2bf(areg[i][0]); o[1] = f2bf(areg[i][1]);
            o[2] = f2bf(areg[i][2]); o[3] = f2bf(areg[i][3]);
            *(us4*)(&As[r * 72 + c4]) = o;
        }
        __syncthreads();                       // drain loads, tile ready
#pragma unroll
        for (int ks = 0; ks < 64; ks += 32) {
            bf16x8 af[2], bfr[4];
#pragma unroll
            for (int mf = 0; mf < 2; mf++)
                af[mf] = *(const bf16x8*)(&As[(mf * 16 + lr) * 72 + ks + lq * 8]);
#pragma unroll
            for (int nf = 0; nf < 4; nf++) {
                int rb = (nf < 2) ? (wave * 32 + nf * 16 + lr)
                                  : (128 + wave * 32 + (nf - 2) * 16 + lr);
                bfr[nf] = *(const bf16x8*)(&Bs[rb * 64 + ((ks + lq * 8) ^ ((rb & 7) << 3))]);
            }
#pragma unroll
            for (int mf = 0; mf < 2; mf++)
#pragma unroll
                for (int nf = 0; nf < 4; nf++)
                    acc[mf][nf] = __builtin_amdgcn_mfma_f32_16x16x32_bf16(
                        af[mf], bfr[nf], acc[mf][nf], 0, 0, 0);
        }
    }

    // ---- epilogue: eK/eKV + transpose via LDS (overlay on Bs), bf16 write
    __syncthreads();                           // last compute done
    unsigned short* ekvS = &Bs[0];             // [128][40]
    unsigned short* ekS  = ekvS + 128 * 40;    // [128][40]
#pragma unroll
    for (int nf = 0; nf < 2; nf++) {
        int h = wave * 32 + nf * 16 + lr;      // [0,128)
        float bk = wk_b[h], bv = wv_b[h];
#pragma unroll
        for (int mf = 0; mf < 2; mf++) {
            int m = mf * 16 + lq * 4;          // [0,32)
            us4 ok, okv;
#pragma unroll
            for (int j = 0; j < 4; j++) {
                float ek = __expf(acc[mf][nf][j] + bk);
                float vv = acc[mf][nf + 2][j] + bv;
                ok[j]  = f2bf(ek);
                okv[j] = f2bf(ek * vv);
            }
            *(us4*)(ekS  + h * 40 + m) = ok;
            *(us4*)(ekvS + h * 40 + m) = okv;
        }
    }
    __syncthreads();
    unsigned short* dst = KVc + (size_t)bb * 256 * T_;
#pragma unroll
    for (int i = 0; i < 2; i++) {
        int c = i * 256 + tid;                 // 512 us8 chunks per array
        int h = c >> 2, mc = (c & 3) * 8;
        us8 vkv = *(const us8*)(ekvS + h * 40 + mc);
        us8 vk  = *(const us8*)(ekS  + h * 40 + mc);
        *(us8*)(dst + (size_t)h * T_ + t0 + mc)         = vkv;   // num rows
        *(us8*)(dst + (size_t)(128 + h) * T_ + t0 + mc) = vk;    // den rows
    }
}

// ---------------------------------------------------------------- gemm2
// out[b][t][h] = (ew[t,:] @ eKV^T[h,:]) / (ew[t,:] @ eK^T[h,:])
// BM=32 (t), BN=256 (128 num + 128 den), BK=64, K=2048, 4 waves.
// Wave w: num cols [w*32,w*32+32), den cols [128+w*32,...): divide is
// register-local. Grid 64x8 = 512 blocks, LDS 36KB single-buffer.
__global__ __launch_bounds__(256) void gemm2(const unsigned short* __restrict__ ew,
                                             const unsigned short* __restrict__ KVc,
                                             float* __restrict__ out) {
    __shared__ __align__(16) unsigned short As[32 * 64];
    __shared__ __align__(16) unsigned short Bs[256 * 64];
    const int tid  = threadIdx.x;
    const int t0   = blockIdx.x * 32;
    const int b    = blockIdx.y;
    const unsigned short* Bsrc = KVc + (size_t)b * 256 * T_;
    const int wave = tid >> 6, lane = tid & 63;
    const int lr = lane & 15, lq = lane >> 4;

    f32x4 acc[2][4];
#pragma unroll
    for (int i = 0; i < 2; i++)
#pragma unroll
        for (int j = 0; j < 4; j++) acc[i][j] = {0.f, 0.f, 0.f, 0.f};

    for (int t = 0; t < 32; t++) {
        int k0 = t * 64;
        __syncthreads();
        // A: 32x64 bf16 (256 x 16B chunks, one per thread)
        {
            int c = tid, r = c >> 3, kc = ((c & 7) ^ (r & 7)) * 8;
            gload16(ew + (size_t)(t0 + r) * T_ + k0 + kc, &As[(wave * 64) * 8]);
        }
        // B: 256x64 bf16
#pragma unroll
        for (int i = 0; i < 8; i++) {
            int c = i * 256 + tid, r = c >> 3, kc = ((c & 7) ^ (r & 7)) * 8;
            gload16(Bsrc + (size_t)r * T_ + k0 + kc, &Bs[(i * 256 + wave * 64) * 8]);
        }
        __syncthreads();
#pragma unroll
        for (int ks = 0; ks < 64; ks += 32) {
            bf16x8 af[2], bfr[4];
#pragma unroll
            for (int mf = 0; mf < 2; mf++) {
                int ra = mf * 16 + lr;
                af[mf] = *(const bf16x8*)(&As[ra * 64 + ((ks + lq * 8) ^ ((ra & 7) << 3))]);
            }
#pragma unroll
            for (int nf = 0; nf < 4; nf++) {
                int rb = (nf < 2) ? (wave * 32 + nf * 16 + lr)
                                  : (128 + wave * 32 + (nf - 2) * 16 + lr);
                bfr[nf] = *(const bf16x8*)(&Bs[rb * 64 + ((ks + lq * 8) ^ ((rb & 7) << 3))]);
            }
#pragma unroll
            for (int mf = 0; mf < 2; mf++)
#pragma unroll
                for (int nf = 0; nf < 4; nf++)
                    acc[mf][nf] = __builtin_amdgcn_mfma_f32_16x16x32_bf16(
                        af[mf], bfr[nf], acc[mf][nf], 0, 0, 0);
        }
    }

    // ---- epilogue: register-local divide, fp32 store
    float* ob = out + ((size_t)b * T_ + t0) * HID_;
#pragma unroll
    for (int nf = 0; nf < 2; nf++) {
        int h = wave * 32 + nf * 16 + lr;
#pragma unroll
        for (int mf = 0; mf < 2; mf++) {
            int m = mf * 16 + lq * 4;
#pragma unroll
            for (int j = 0; j < 4; j++)
                ob[(size_t)(m + j) * HID_ + h] = acc[mf][nf][j] / acc[mf][nf + 2][j];
        }
    }
}

// ---------------------------------------------------------------- launch
extern "C" void kernel_launch(void* const* d_in, const int* in_sizes, int n_in,
                              void* d_out, int out_size, void* d_ws, size_t ws_size,
                              hipStream_t stream) {
    const float* x    = (const float*)d_in[0];
    const float* wk_w = (const float*)d_in[1];
    const float* wk_b = (const float*)d_in[2];
    const float* wv_w = (const float*)d_in[3];
    const float* wv_b = (const float*)d_in[4];
    const float* w    = (const float*)d_in[5];

    char* ws = (char*)d_ws;
    unsigned short* ws_ew   = (unsigned short*)(ws);                 // 8 MiB [2048][2048]
    unsigned short* ws_wkvT = (unsigned short*)(ws + (8u << 20));    // 0.5 MiB [256][1024]
    unsigned short* ws_KVc  = (unsigned short*)(ws + (9u << 20));    // 8 MiB [8][256][2048]

    prep_ew  <<<4096, 256, 0, stream>>>(w, ws_ew);
    prep_wkv <<<1024, 256, 0, stream>>>(wk_w, wv_w, ws_wkvT);
    gemm1    <<<512, 256, 0, stream>>>(x, ws_wkvT, wk_b, wv_b, ws_KVc);
    gemm2    <<<dim3(64, 8), 256, 0, stream>>>(ws_ew, ws_KVc, (float*)d_out);
}

// Round 8
// 165.583 us; speedup vs baseline: 1.1398x; 1.0146x over previous
//
#include <hip/hip_runtime.h>
#include <hip/hip_bf16.h>

// AFT-Full: out = (exp(w) @ (exp(K)*V)) / (exp(w) @ exp(K)),  K,V = x@W+b
// B=8, T=2048, DIM=1024, HID=128. fp32 in/out; bf16 MFMA internally.
// R6: T3+T4 minimum 2-phase — double-buffered LDS + counted s_waitcnt vmcnt(N)
//     (never 0 in loop) + raw s_barrier, while keeping 2 blocks/CU (LDS<75KB).

#define T_    2048
#define DIM_  1024
#define HID_  128

typedef __attribute__((ext_vector_type(8))) __bf16 bf16x8;
typedef __attribute__((ext_vector_type(4))) float f32x4;
typedef __attribute__((ext_vector_type(4))) unsigned short us4;
typedef __attribute__((ext_vector_type(8))) unsigned short us8;

typedef const unsigned int __attribute__((address_space(1)))* gas_t;
typedef unsigned int __attribute__((address_space(3)))* las_t;

__device__ __forceinline__ unsigned short f2bf(float f) {
    unsigned int u = __builtin_bit_cast(unsigned int, f);
    u += 0x7fffu + ((u >> 16) & 1u);   // RNE
    return (unsigned short)(u >> 16);
}

__device__ __forceinline__ void gload16(const void* g, void* l) {
    __builtin_amdgcn_global_load_lds((gas_t)g, (las_t)l, 16, 0, 0);
}

// ---------------------------------------------------------------- prep_ew
__global__ __launch_bounds__(256) void prep_ew(const float* __restrict__ w,
                                               unsigned short* __restrict__ ew) {
    int idx = blockIdx.x * 256 + threadIdx.x;   // float4 index, 1M total
    f32x4 v = ((const f32x4*)w)[idx];
    us4 o;
    o[0] = f2bf(__expf(v[0]));
    o[1] = f2bf(__expf(v[1]));
    o[2] = f2bf(__expf(v[2]));
    o[3] = f2bf(__expf(v[3]));
    ((us4*)ew)[idx] = o;
}

// ---------------------------------------------------------------- prep_wkv
// wkvT[n][k]: n<128 -> wk_w[k][n], else wv_w[k][n-128]   (256 x 1024 bf16)
// Thread handles one n and 8 consecutive k (us8 write).
__global__ __launch_bounds__(256) void prep_wkv(const float* __restrict__ wk,
                                                const float* __restrict__ wv,
                                                unsigned short* __restrict__ wkvT) {
    int t = blockIdx.x * 256 + threadIdx.x;     // 32768 threads
    int n = t & 255, k0 = (t >> 8) << 3;
    const float* src = (n < 128) ? (wk + n) : (wv + (n - 128));
    us8 o;
#pragma unroll
    for (int j = 0; j < 8; j++) o[j] = f2bf(src[(size_t)(k0 + j) * 128]);
    *(us8*)(&wkvT[n * 1024 + k0]) = o;
}

// ---------------------------------------------------------------- gemm1
// K|V = x @ wkvT^T (+bias) for a 32-row tile; epilogue: eK=exp(K),
// eKV=eK*V, transposed bf16 write into KVc[b]:
//   rows 0..127   = (eK*V)^T  (num), rows 128..255 = (eK)^T (den)
// BM=32, BN=256, BK=64, 4 waves. Counted-vmcnt dbuf pipeline:
// per iter: issue A(t+1)->regs (2) + B(t+1)->LDS (8); vmcnt(10) => tile-t
// landed; convert A(t) regs -> As[cur]; lgkmcnt(0); barrier; MFMA; barrier.
__global__ __launch_bounds__(256) void gemm1(const float* __restrict__ x,
                                             const unsigned short* __restrict__ wkvT,
                                             const float* __restrict__ wk_b,
                                             const float* __restrict__ wv_b,
                                             unsigned short* __restrict__ KVc) {
    __shared__ __align__(16) unsigned short As[2][32 * 72];    // padded (ds_write)
    __shared__ __align__(16) unsigned short Bs[2][256 * 64];   // linear (gload_lds)
    const int tid  = threadIdx.x;
    const int m0   = blockIdx.x * 32;          // [0,16384)
    const int bb   = m0 >> 11;
    const int t0   = m0 & (T_ - 1);
    const int wave = tid >> 6, lane = tid & 63;
    const int lr = lane & 15, lq = lane >> 4;

    f32x4 acc[2][4];
#pragma unroll
    for (int i = 0; i < 2; i++)
#pragma unroll
        for (int j = 0; j < 4; j++) acc[i][j] = {0.f, 0.f, 0.f, 0.f};

    f32x4 aC[2], aN[2];
    // ---- prologue: issue tile-0 loads (no waits here; loop iter 0 waits)
#pragma unroll
    for (int i = 0; i < 2; i++) {
        int c = i * 256 + tid, r = c >> 4, c4 = (c & 15) * 4;
        aC[i] = *(const f32x4*)(x + (size_t)(m0 + r) * DIM_ + c4);
    }
#pragma unroll
    for (int i = 0; i < 8; i++) {
        int c = i * 256 + tid, r = c >> 3, kc = ((c & 7) ^ (r & 7)) * 8;
        gload16(wkvT + (size_t)r * DIM_ + kc, &Bs[0][(i * 256 + wave * 64) * 8]);
    }

    int cur = 0;
    for (int t = 0; t < 16; t++) {
        if (t < 15) {
            int k0 = (t + 1) * 64;
#pragma unroll
            for (int i = 0; i < 2; i++) {
                int c = i * 256 + tid, r = c >> 4, c4 = (c & 15) * 4;
                aN[i] = *(const f32x4*)(x + (size_t)(m0 + r) * DIM_ + k0 + c4);
            }
#pragma unroll
            for (int i = 0; i < 8; i++) {
                int c = i * 256 + tid, r = c >> 3, kc = ((c & 7) ^ (r & 7)) * 8;
                gload16(wkvT + (size_t)r * DIM_ + k0 + kc,
                        &Bs[cur ^ 1][(i * 256 + wave * 64) * 8]);
            }
            // 10 newest (tile t+1) may stay in flight; everything older done.
            asm volatile("s_waitcnt vmcnt(10)" ::: "memory");
        } else {
            asm volatile("s_waitcnt vmcnt(0)" ::: "memory");
        }
        // convert tile-t A regs -> As[cur]
#pragma unroll
        for (int i = 0; i < 2; i++) {
            int c = i * 256 + tid, r = c >> 4, c4 = (c & 15) * 4;
            us4 o;
            o[0] = f2bf(aC[i][0]); o[1] = f2bf(aC[i][1]);
            o[2] = f2bf(aC[i][2]); o[3] = f2bf(aC[i][3]);
            *(us4*)(&As[cur][r * 72 + c4]) = o;
        }
        asm volatile("s_waitcnt lgkmcnt(0)" ::: "memory");
        __builtin_amdgcn_s_barrier();
#pragma unroll
        for (int ks = 0; ks < 64; ks += 32) {
            bf16x8 af[2], bfr[4];
#pragma unroll
            for (int mf = 0; mf < 2; mf++)
                af[mf] = *(const bf16x8*)(&As[cur][(mf * 16 + lr) * 72 + ks + lq * 8]);
#pragma unroll
            for (int nf = 0; nf < 4; nf++) {
                int rb = (nf < 2) ? (wave * 32 + nf * 16 + lr)
                                  : (128 + wave * 32 + (nf - 2) * 16 + lr);
                bfr[nf] = *(const bf16x8*)(&Bs[cur][rb * 64 + ((ks + lq * 8) ^ ((rb & 7) << 3))]);
            }
#pragma unroll
            for (int mf = 0; mf < 2; mf++)
#pragma unroll
                for (int nf = 0; nf < 4; nf++)
                    acc[mf][nf] = __builtin_amdgcn_mfma_f32_16x16x32_bf16(
                        af[mf], bfr[nf], acc[mf][nf], 0, 0, 0);
        }
        __builtin_amdgcn_s_barrier();
        aC[0] = aN[0]; aC[1] = aN[1];
        cur ^= 1;
    }

    // ---- epilogue: eK/eKV + transpose via LDS (overlay on Bs), bf16 write
    unsigned short* ekvS = &Bs[0][0];          // [128][40]
    unsigned short* ekS  = ekvS + 128 * 40;    // [128][40]
#pragma unroll
    for (int nf = 0; nf < 2; nf++) {
        int h = wave * 32 + nf * 16 + lr;      // [0,128)
        float bk = wk_b[h], bv = wv_b[h];
#pragma unroll
        for (int mf = 0; mf < 2; mf++) {
            int m = mf * 16 + lq * 4;          // [0,32)
            us4 ok, okv;
#pragma unroll
            for (int j = 0; j < 4; j++) {
                float ek = __expf(acc[mf][nf][j] + bk);
                float vv = acc[mf][nf + 2][j] + bv;
                ok[j]  = f2bf(ek);
                okv[j] = f2bf(ek * vv);
            }
            *(us4*)(ekS  + h * 40 + m) = ok;
            *(us4*)(ekvS + h * 40 + m) = okv;
        }
    }
    __syncthreads();
    unsigned short* dst = KVc + (size_t)bb * 256 * T_;
#pragma unroll
    for (int i = 0; i < 2; i++) {
        int c = i * 256 + tid;                 // 512 us8 chunks per array
        int h = c >> 2, mc = (c & 3) * 8;
        us8 vkv = *(const us8*)(ekvS + h * 40 + mc);
        us8 vk  = *(const us8*)(ekS  + h * 40 + mc);
        *(us8*)(dst + (size_t)h * T_ + t0 + mc)         = vkv;   // num rows
        *(us8*)(dst + (size_t)(128 + h) * T_ + t0 + mc) = vk;    // den rows
    }
}

// ---------------------------------------------------------------- gemm2
// out[b][t][h] = (ew[t,:] @ eKV^T[h,:]) / (ew[t,:] @ eK^T[h,:])
// BM=32 (t), BN=256 (128 num + 128 den), BK=64, K=2048, 4 waves.
// Counted-vmcnt dbuf: STAGE(nxt); vmcnt(9); barrier; MFMA(cur); barrier.
__global__ __launch_bounds__(256) void gemm2(const unsigned short* __restrict__ ew,
                                             const unsigned short* __restrict__ KVc,
                                             float* __restrict__ out) {
    __shared__ __align__(16) unsigned short As[2][32 * 64];
    __shared__ __align__(16) unsigned short Bs[2][256 * 64];
    const int tid  = threadIdx.x;
    const int t0   = blockIdx.x * 32;
    const int b    = blockIdx.y;
    const unsigned short* Bsrc = KVc + (size_t)b * 256 * T_;
    const int wave = tid >> 6, lane = tid & 63;
    const int lr = lane & 15, lq = lane >> 4;

    f32x4 acc[2][4];
#pragma unroll
    for (int i = 0; i < 2; i++)
#pragma unroll
        for (int j = 0; j < 4; j++) acc[i][j] = {0.f, 0.f, 0.f, 0.f};

#define STAGE2(BUF, K0) do {                                                      \
    { int c = tid, r = c >> 3, kc = ((c & 7) ^ (r & 7)) * 8;                      \
      gload16(ew + (size_t)(t0 + r) * T_ + (K0) + kc, &As[BUF][(wave * 64) * 8]); } \
    _Pragma("unroll")                                                             \
    for (int i = 0; i < 8; i++) {                                                 \
        int c = i * 256 + tid, r = c >> 3, kc = ((c & 7) ^ (r & 7)) * 8;          \
        gload16(Bsrc + (size_t)r * T_ + (K0) + kc,                                \
                &Bs[BUF][(i * 256 + wave * 64) * 8]);                             \
    } } while (0)

    // ---- prologue: issue tile-0 loads
    STAGE2(0, 0);

    int cur = 0;
    for (int t = 0; t < 32; t++) {
        if (t < 31) {
            STAGE2(cur ^ 1, (t + 1) * 64);
            asm volatile("s_waitcnt vmcnt(9)" ::: "memory");   // tile t landed
        } else {
            asm volatile("s_waitcnt vmcnt(0)" ::: "memory");
        }
        __builtin_amdgcn_s_barrier();
#pragma unroll
        for (int ks = 0; ks < 64; ks += 32) {
            bf16x8 af[2], bfr[4];
#pragma unroll
            for (int mf = 0; mf < 2; mf++) {
                int ra = mf * 16 + lr;
                af[mf] = *(const bf16x8*)(&As[cur][ra * 64 + ((ks + lq * 8) ^ ((ra & 7) << 3))]);
            }
#pragma unroll
            for (int nf = 0; nf < 4; nf++) {
                int rb = (nf < 2) ? (wave * 32 + nf * 16 + lr)
                                  : (128 + wave * 32 + (nf - 2) * 16 + lr);
                bfr[nf] = *(const bf16x8*)(&Bs[cur][rb * 64 + ((ks + lq * 8) ^ ((rb & 7) << 3))]);
            }
#pragma unroll
            for (int mf = 0; mf < 2; mf++)
#pragma unroll
                for (int nf = 0; nf < 4; nf++)
                    acc[mf][nf] = __builtin_amdgcn_mfma_f32_16x16x32_bf16(
                        af[mf], bfr[nf], acc[mf][nf], 0, 0, 0);
        }
        __builtin_amdgcn_s_barrier();
        cur ^= 1;
    }
#undef STAGE2

    // ---- epilogue: register-local divide, fp32 store
    float* ob = out + ((size_t)b * T_ + t0) * HID_;
#pragma unroll
    for (int nf = 0; nf < 2; nf++) {
        int h = wave * 32 + nf * 16 + lr;
#pragma unroll
        for (int mf = 0; mf < 2; mf++) {
            int m = mf * 16 + lq * 4;
#pragma unroll
            for (int j = 0; j < 4; j++)
                ob[(size_t)(m + j) * HID_ + h] = acc[mf][nf][j] / acc[mf][nf + 2][j];
        }
    }
}

// ---------------------------------------------------------------- launch
extern "C" void kernel_launch(void* const* d_in, const int* in_sizes, int n_in,
                              void* d_out, int out_size, void* d_ws, size_t ws_size,
                              hipStream_t stream) {
    const float* x    = (const float*)d_in[0];
    const float* wk_w = (const float*)d_in[1];
    const float* wk_b = (const float*)d_in[2];
    const float* wv_w = (const float*)d_in[3];
    const float* wv_b = (const float*)d_in[4];
    const float* w    = (const float*)d_in[5];

    char* ws = (char*)d_ws;
    unsigned short* ws_ew   = (unsigned short*)(ws);                 // 8 MiB [2048][2048]
    unsigned short* ws_wkvT = (unsigned short*)(ws + (8u << 20));    // 0.5 MiB [256][1024]
    unsigned short* ws_KVc  = (unsigned short*)(ws + (9u << 20));    // 8 MiB [8][256][2048]

    prep_ew  <<<4096, 256, 0, stream>>>(w, ws_ew);
    prep_wkv <<<128,  256, 0, stream>>>(wk_w, wv_w, ws_wkvT);
    gemm1    <<<512,  256, 0, stream>>>(x, ws_wkvT, wk_b, wv_b, ws_KVc);
    gemm2    <<<dim3(64, 8), 256, 0, stream>>>(ws_ew, ws_KVc, (float*)d_out);
}